// Round 1
// baseline (2366.345 us; speedup 1.0000x reference)
//
#include <hip/hip_runtime.h>

// CrossAttention (linear attention, no softmax):
//   S = K1^T V1 + K2^T V2 per (b,h)  [64x64]  -- shared by both outputs
//   attn_i = Q_i @ S; x = LN(inp + attn@Wo^T+bo); out = LN(x + FF(x))
// B=4, L=2048, D=512, H=8, Dh=64, PF=2048. All fp32.

#define Bq 4
#define Lq 2048
#define Dq 512
#define Hq 8
#define PFq 2048
#define Mrows 8192            // B*L
#define WS_M4 4194304ull      // 8192*512 floats per buffer

// ---------------- generic tiled GEMM: C = A[M,K] @ W[N,K]^T + bias (+R)(+relu) ----
__global__ __launch_bounds__(256) void gemm_nt(
    const float* __restrict__ A, const float* __restrict__ W,
    const float* __restrict__ bias, const float* __restrict__ R,
    float* __restrict__ C, int M, int N, int K, int do_relu)
{
    __shared__ float As[64][33];
    __shared__ float Ws[64][33];
    const int tid = threadIdx.x;
    const int tx = tid & 15, ty = tid >> 4;
    const int bm = blockIdx.y * 64, bn = blockIdx.x * 64;
    float acc[4][4] = {};
    for (int k0 = 0; k0 < K; k0 += 32) {
#pragma unroll
        for (int it = 0; it < 2; ++it) {
            int e = tid + it * 256;          // float4 index 0..511
            int row = e >> 3;                // 8 float4 per 32-float row
            int c4 = (e & 7) << 2;
            float4 a = *(const float4*)(A + (size_t)(bm + row) * K + k0 + c4);
            As[row][c4 + 0] = a.x; As[row][c4 + 1] = a.y;
            As[row][c4 + 2] = a.z; As[row][c4 + 3] = a.w;
            float4 w = *(const float4*)(W + (size_t)(bn + row) * K + k0 + c4);
            Ws[row][c4 + 0] = w.x; Ws[row][c4 + 1] = w.y;
            Ws[row][c4 + 2] = w.z; Ws[row][c4 + 3] = w.w;
        }
        __syncthreads();
#pragma unroll
        for (int kk = 0; kk < 32; ++kk) {
            float av[4], wv[4];
#pragma unroll
            for (int i = 0; i < 4; ++i) av[i] = As[ty * 4 + i][kk];
#pragma unroll
            for (int j = 0; j < 4; ++j) wv[j] = Ws[tx * 4 + j][kk];
#pragma unroll
            for (int i = 0; i < 4; ++i)
#pragma unroll
                for (int j = 0; j < 4; ++j)
                    acc[i][j] = fmaf(av[i], wv[j], acc[i][j]);
        }
        __syncthreads();
    }
#pragma unroll
    for (int i = 0; i < 4; ++i) {
        int m = bm + ty * 4 + i;
#pragma unroll
        for (int j = 0; j < 4; ++j) {
            int n = bn + tx * 4 + j;
            float v = acc[i][j] + bias[n];
            if (R) v += R[(size_t)m * N + n];
            if (do_relu) v = fmaxf(v, 0.f);
            C[(size_t)m * N + n] = v;
        }
    }
}

// ---------------- zero small buffer ----------------
__global__ __launch_bounds__(256) void zero_kernel(float* __restrict__ p)
{
    int idx = blockIdx.x * 256 + threadIdx.x;
    *(float4*)(p + (size_t)idx * 4) = make_float4(0.f, 0.f, 0.f, 0.f);
}

// ---------------- S[b,h] += sum_l K[l]^T outer V[l] (both inputs) ----------------
// grid: (B*H, 16 chunks of 128 rows), block 256
__global__ __launch_bounds__(256) void s_kernel(
    const float* __restrict__ K1, const float* __restrict__ V1,
    const float* __restrict__ K2, const float* __restrict__ V2,
    float* __restrict__ S)
{
    const int bh = blockIdx.x;           // b*8+h
    const int chunk = blockIdx.y;        // 0..15
    const int b = bh >> 3, h = bh & 7;
    __shared__ float Ks[8][64];
    __shared__ float Vs[8][64];
    const int tid = threadIdx.x;
    const int tx = tid & 15, ty = tid >> 4;
    float acc[4][4] = {};
    for (int pass = 0; pass < 2; ++pass) {
        const float* Kp = pass ? K2 : K1;
        const float* Vp = pass ? V2 : V1;
        for (int l0 = 0; l0 < 128; l0 += 8) {
#pragma unroll
            for (int it = 0; it < 2; ++it) {
                int e = tid + it * 256;          // 0..511
                int rr = e >> 6, cc = e & 63;
                size_t g = ((size_t)b * Lq + chunk * 128 + l0 + rr) * Dq + h * 64 + cc;
                Ks[rr][cc] = Kp[g];
                Vs[rr][cc] = Vp[g];
            }
            __syncthreads();
#pragma unroll
            for (int rr = 0; rr < 8; ++rr) {
                float kv[4], vv[4];
#pragma unroll
                for (int i = 0; i < 4; ++i) kv[i] = Ks[rr][ty * 4 + i];
#pragma unroll
                for (int j = 0; j < 4; ++j) vv[j] = Vs[rr][tx * 4 + j];
#pragma unroll
                for (int i = 0; i < 4; ++i)
#pragma unroll
                    for (int j = 0; j < 4; ++j)
                        acc[i][j] = fmaf(kv[i], vv[j], acc[i][j]);
            }
            __syncthreads();
        }
    }
#pragma unroll
    for (int i = 0; i < 4; ++i)
#pragma unroll
        for (int j = 0; j < 4; ++j)
            atomicAdd(&S[((size_t)bh * 64 + ty * 4 + i) * 64 + tx * 4 + j], acc[i][j]);
}

// ---------------- attn = Q_head @ S[b,h]  (per head, [L,64]x[64,64]) ----------------
// grid: (B*H, L/64), block 256
__global__ __launch_bounds__(256) void attn_kernel(
    const float* __restrict__ Q, const float* __restrict__ S, float* __restrict__ O)
{
    const int bh = blockIdx.x;
    const int lt = blockIdx.y;
    const int b = bh >> 3, h = bh & 7;
    __shared__ float Ss[64][65];
    __shared__ float Qs[64][65];
    const int tid = threadIdx.x;
    const int tx = tid & 15, ty = tid >> 4;
    const float* Sp = S + (size_t)bh * 4096;
#pragma unroll
    for (int it = 0; it < 4; ++it) {
        int e = tid + it * 256;              // float4 idx 0..1023
        int row = e >> 4, c4 = (e & 15) << 2;
        float4 s = *(const float4*)(Sp + (size_t)row * 64 + c4);
        Ss[row][c4 + 0] = s.x; Ss[row][c4 + 1] = s.y;
        Ss[row][c4 + 2] = s.z; Ss[row][c4 + 3] = s.w;
        float4 q = *(const float4*)(Q + ((size_t)b * Lq + lt * 64 + row) * Dq + h * 64 + c4);
        Qs[row][c4 + 0] = q.x; Qs[row][c4 + 1] = q.y;
        Qs[row][c4 + 2] = q.z; Qs[row][c4 + 3] = q.w;
    }
    __syncthreads();
    float acc[4][4] = {};
#pragma unroll
    for (int dk = 0; dk < 64; ++dk) {
        float qv[4], sv[4];
#pragma unroll
        for (int i = 0; i < 4; ++i) qv[i] = Qs[ty * 4 + i][dk];
#pragma unroll
        for (int j = 0; j < 4; ++j) sv[j] = Ss[dk][tx * 4 + j];
#pragma unroll
        for (int i = 0; i < 4; ++i)
#pragma unroll
            for (int j = 0; j < 4; ++j)
                acc[i][j] = fmaf(qv[i], sv[j], acc[i][j]);
    }
#pragma unroll
    for (int i = 0; i < 4; ++i)
#pragma unroll
        for (int j = 0; j < 4; ++j)
            O[((size_t)b * Lq + lt * 64 + ty * 4 + i) * Dq + h * 64 + tx * 4 + j] = acc[i][j];
}

// ---------------- LayerNorm in place, row of 512, two-pass ----------------
__global__ __launch_bounds__(256) void ln_inplace(
    float* __restrict__ X, const float* __restrict__ g, const float* __restrict__ bta)
{
    __shared__ float red[256];
    const int row = blockIdx.x;
    const int t = threadIdx.x;
    float* xr = X + (size_t)row * Dq;
    float v0 = xr[t], v1 = xr[t + 256];
    red[t] = v0 + v1;
    __syncthreads();
    for (int s = 128; s > 0; s >>= 1) { if (t < s) red[t] += red[t + s]; __syncthreads(); }
    float mean = red[0] * (1.f / Dq);
    __syncthreads();
    float d0 = v0 - mean, d1 = v1 - mean;
    red[t] = d0 * d0 + d1 * d1;
    __syncthreads();
    for (int s = 128; s > 0; s >>= 1) { if (t < s) red[t] += red[t + s]; __syncthreads(); }
    float rstd = rsqrtf(red[0] * (1.f / Dq) + 1e-5f);
    xr[t] = d0 * rstd * g[t] + bta[t];
    xr[t + 256] = d1 * rstd * g[t + 256] + bta[t + 256];
}

// ---------------- LayerNorm row -> output (stride 1024, column offset) --------
__global__ __launch_bounds__(256) void ln_to_out(
    const float* __restrict__ Y, const float* __restrict__ g, const float* __restrict__ bta,
    float* __restrict__ out, int halfOff)
{
    __shared__ float red[256];
    const int row = blockIdx.x;
    const int t = threadIdx.x;
    const float* yr = Y + (size_t)row * Dq;
    float v0 = yr[t], v1 = yr[t + 256];
    red[t] = v0 + v1;
    __syncthreads();
    for (int s = 128; s > 0; s >>= 1) { if (t < s) red[t] += red[t + s]; __syncthreads(); }
    float mean = red[0] * (1.f / Dq);
    __syncthreads();
    float d0 = v0 - mean, d1 = v1 - mean;
    red[t] = d0 * d0 + d1 * d1;
    __syncthreads();
    for (int s = 128; s > 0; s >>= 1) { if (t < s) red[t] += red[t + s]; __syncthreads(); }
    float rstd = rsqrtf(red[0] * (1.f / Dq) + 1e-5f);
    float* orow = out + (size_t)row * 1024 + halfOff;
    orow[t] = d0 * rstd * g[t] + bta[t];
    orow[t + 256] = d1 * rstd * g[t + 256] + bta[t + 256];
}

extern "C" void kernel_launch(void* const* d_in, const int* in_sizes, int n_in,
                              void* d_out, int out_size, void* d_ws, size_t ws_size,
                              hipStream_t stream)
{
    const float* question = (const float*)d_in[0];
    const float* query    = (const float*)d_in[1];
    const float* Wq = (const float*)d_in[2];  const float* bq = (const float*)d_in[3];
    const float* Wk = (const float*)d_in[4];  const float* bk = (const float*)d_in[5];
    const float* Wv = (const float*)d_in[6];  const float* bv = (const float*)d_in[7];
    const float* Wo = (const float*)d_in[8];  const float* bo = (const float*)d_in[9];
    const float* ln_g = (const float*)d_in[10]; const float* ln_b = (const float*)d_in[11];
    const float* W1 = (const float*)d_in[12]; const float* b1 = (const float*)d_in[13];
    const float* W2 = (const float*)d_in[14]; const float* b2 = (const float*)d_in[15];
    float* out = (float*)d_out;
    float* ws  = (float*)d_ws;

    // ws layout (floats): 6 x [8192,512] QKV buffers, then S [32,64,64].
    float* Q1 = ws + 0 * WS_M4;
    float* K1 = ws + 1 * WS_M4;
    float* V1 = ws + 2 * WS_M4;
    float* Q2 = ws + 3 * WS_M4;
    float* K2 = ws + 4 * WS_M4;
    float* V2 = ws + 5 * WS_M4;
    float* S  = ws + 6 * WS_M4;      // 131072 floats
    float* attn1 = K1;               // K dead after S
    float* attn2 = K2;
    float* x1 = V1;                  // V dead after S
    float* x2 = V2;
    float* hbuf = ws;                // Q1+K1 regions = exactly 4096*2048 floats

    dim3 blk(256);

    // QKV projections (M=8192, N=512, K=512)
    gemm_nt<<<dim3(8, 128), blk, 0, stream>>>(question, Wq, bq, nullptr, Q1, Mrows, Dq, Dq, 0);
    gemm_nt<<<dim3(8, 128), blk, 0, stream>>>(question, Wk, bk, nullptr, K1, Mrows, Dq, Dq, 0);
    gemm_nt<<<dim3(8, 128), blk, 0, stream>>>(question, Wv, bv, nullptr, V1, Mrows, Dq, Dq, 0);
    gemm_nt<<<dim3(8, 128), blk, 0, stream>>>(query,    Wq, bq, nullptr, Q2, Mrows, Dq, Dq, 0);
    gemm_nt<<<dim3(8, 128), blk, 0, stream>>>(query,    Wk, bk, nullptr, K2, Mrows, Dq, Dq, 0);
    gemm_nt<<<dim3(8, 128), blk, 0, stream>>>(query,    Wv, bv, nullptr, V2, Mrows, Dq, Dq, 0);

    // S = K1^T V1 + K2^T V2 per (b,h)
    zero_kernel<<<128, blk, 0, stream>>>(S);
    s_kernel<<<dim3(Bq * Hq, 16), blk, 0, stream>>>(K1, V1, K2, V2, S);

    // attn = Q @ S (overwrites K buffers)
    attn_kernel<<<dim3(Bq * Hq, Lq / 64), blk, 0, stream>>>(Q1, S, attn1);
    attn_kernel<<<dim3(Bq * Hq, Lq / 64), blk, 0, stream>>>(Q2, S, attn2);

    // x = attn @ Wo^T + bo + inp  (overwrites V buffers), then LN in place
    gemm_nt<<<dim3(8, 128), blk, 0, stream>>>(attn1, Wo, bo, question, x1, Mrows, Dq, Dq, 0);
    gemm_nt<<<dim3(8, 128), blk, 0, stream>>>(attn2, Wo, bo, query,    x2, Mrows, Dq, Dq, 0);
    ln_inplace<<<Mrows, blk, 0, stream>>>(x1, ln_g, ln_b);
    ln_inplace<<<Mrows, blk, 0, stream>>>(x2, ln_g, ln_b);

    // FFN per input, chunked by 4096 rows (h reuses Q1/attn1 region)
    for (int half = 0; half < 2; ++half) {
        float* x = half ? x2 : x1;
        for (int c = 0; c < 2; ++c) {
            float* xc = x + (size_t)c * 4096 * Dq;
            // h = relu(xc @ W1^T + b1): M=4096, N=2048, K=512
            gemm_nt<<<dim3(32, 64), blk, 0, stream>>>(xc, W1, b1, nullptr, hbuf, 4096, PFq, Dq, 1);
            // y = h @ W2^T + b2 + xc -> in place into xc: M=4096, N=512, K=2048
            gemm_nt<<<dim3(8, 64), blk, 0, stream>>>(hbuf, W2, b2, xc, xc, 4096, Dq, PFq, 0);
        }
        // final LN -> out half columns
        ln_to_out<<<Mrows, blk, 0, stream>>>(x, ln_g, ln_b, out, half * Dq);
    }
}

// Round 2
// 700.869 us; speedup vs baseline: 3.3763x; 3.3763x over previous
//
#include <hip/hip_runtime.h>
#include <stdint.h>

// CrossAttention via linear-attention algebra:
//   S = K1^T V1 + K2^T V2 (per b,h; 64x64), shared by both outputs.
//   attn_i = Q_i @ S ; x = LN(inp + attn@Wo^T+bo) ; out = LN(x + FF(x))
// GEMMs in bf16 MFMA (fp32 accum), m97 structure: 128x128 tile, BK=32,
// global_load_lds width=16, mfma_f32_16x16x32_bf16.

#define Bq 4
#define Lq 2048
#define Dq 512
#define PFq 2048
#define Mrows 8192
#define MiBu 1048576ull

typedef __attribute__((ext_vector_type(8))) short frag_ab;
typedef __attribute__((ext_vector_type(4))) float frag_cd;

__device__ __forceinline__ unsigned short f2b(float f) {
    union { float f; uint32_t u; } x; x.f = f;
    uint32_t r = x.u + 0x7fffu + ((x.u >> 16) & 1u);
    return (unsigned short)(r >> 16);
}
__device__ __forceinline__ float b2f(unsigned short u) {
    union { uint32_t u; float f; } x; x.u = ((uint32_t)u) << 16;
    return x.f;
}

#define GLD16(g, l)                                                              \
    __builtin_amdgcn_global_load_lds(                                            \
        (const __attribute__((address_space(1))) void*)(const void*)(g),         \
        (__attribute__((address_space(3))) void*)(void*)(l), 16, 0, 0)

// ---------- bf16 MFMA GEMM: out = A[M,K]b @ W[N,K]b^T + bias (+R)(+relu) ------
// grid (N/128, M/128), block 256 (4 waves, each 64x64 of the 128x128 tile)
__global__ __launch_bounds__(256) void gemm_bf16(
    const unsigned short* __restrict__ A, const unsigned short* __restrict__ Wt,
    const float* __restrict__ bias, const float* __restrict__ R,
    float* __restrict__ outF, unsigned short* __restrict__ outB,
    int M, int N, int K, int relu)
{
    __shared__ __align__(16) unsigned short At[128 * 32];
    __shared__ __align__(16) unsigned short Bt[128 * 32];
    const int tid = threadIdx.x;
    const int lane = tid & 63;
    const int w = tid >> 6;                 // wave 0..3
    const int wm = (w >> 1) * 64, wn = (w & 1) * 64;
    const int lr = lane & 15;
    const int quad = lane >> 4;             // 0..3
    const size_t bm = (size_t)blockIdx.y * 128, bn = (size_t)blockIdx.x * 128;

    frag_cd acc[4][4] = {};

    // staging: thread covers 8 consecutive bf16; 2 issues per tile (rows 0..63, 64..127)
    const int e = tid * 8;
    const int ar = e >> 5, ac = e & 31;
    const unsigned short* Ag  = A  + (bm + ar) * (size_t)K + ac;
    const unsigned short* Bg  = Wt + (bn + ar) * (size_t)K + ac;
    const unsigned short* Ag2 = Ag + (size_t)64 * K;
    const unsigned short* Bg2 = Bg + (size_t)64 * K;
    unsigned short* Asd = At + w * 512;     // wave-uniform base (+lane*16B implicit)
    unsigned short* Bsd = Bt + w * 512;

    for (int k0 = 0; k0 < K; k0 += 32) {
        __syncthreads();
        GLD16(Ag  + k0, Asd);
        GLD16(Ag2 + k0, Asd + 2048);
        GLD16(Bg  + k0, Bsd);
        GLD16(Bg2 + k0, Bsd + 2048);
        __syncthreads();
        frag_ab a[4], b[4];
#pragma unroll
        for (int i = 0; i < 4; ++i)
            a[i] = *(const frag_ab*)&At[(wm + i * 16 + lr) * 32 + quad * 8];
#pragma unroll
        for (int j = 0; j < 4; ++j)
            b[j] = *(const frag_ab*)&Bt[(wn + j * 16 + lr) * 32 + quad * 8];
#pragma unroll
        for (int i = 0; i < 4; ++i)
#pragma unroll
            for (int j = 0; j < 4; ++j)
                acc[i][j] = __builtin_amdgcn_mfma_f32_16x16x32_bf16(a[i], b[j], acc[i][j], 0, 0, 0);
    }

    // epilogue: C/D layout col=lane&15, row=quad*4+reg
#pragma unroll
    for (int j = 0; j < 4; ++j) {
        const int col = (int)bn + wn + j * 16 + lr;
        const float bv = bias[col];
#pragma unroll
        for (int i = 0; i < 4; ++i) {
            const int rowb = (int)bm + wm + i * 16 + quad * 4;
#pragma unroll
            for (int r = 0; r < 4; ++r) {
                float v = acc[i][j][r] + bv;
                const size_t idx = (size_t)(rowb + r) * N + col;
                if (R) v += R[idx];
                if (relu) v = fmaxf(v, 0.f);
                if (outF) outF[idx] = v;
                if (outB) outB[idx] = f2b(v);
            }
        }
    }
}

// ---------------- fp32 -> bf16 convert (4 elems/thread) ----------------
__global__ __launch_bounds__(256) void convert_bf16(
    const float* __restrict__ in, unsigned short* __restrict__ out)
{
    const size_t idx = (size_t)blockIdx.x * 256 + threadIdx.x;
    float4 v = ((const float4*)in)[idx];
    ushort4 o;
    o.x = f2b(v.x); o.y = f2b(v.y); o.z = f2b(v.z); o.w = f2b(v.w);
    ((ushort4*)out)[idx] = o;
}

// ---------------- build concatenated QKV bias ----------------
__global__ __launch_bounds__(256) void build_bqkv(
    const float* __restrict__ bqp, const float* __restrict__ bkp,
    const float* __restrict__ bvp, float* __restrict__ bqkv)
{
    const int n = blockIdx.x * 256 + threadIdx.x;   // 0..1535
    float v = (n < 512) ? bqp[n] : (n < 1024) ? bkp[n - 512] : bvp[n - 1024];
    bqkv[n] = v;
}

// ---------------- zero S ----------------
__global__ __launch_bounds__(256) void zero_kernel(float* __restrict__ p)
{
    const int idx = blockIdx.x * 256 + threadIdx.x;
    *(float4*)(p + (size_t)idx * 4) = make_float4(0.f, 0.f, 0.f, 0.f);
}

// ------- S[b,h] += K1^T V1 + K2^T V2 (bf16 K/V in QKV buffers, stride 1536) ----
// grid (32 bh, 16 chunks), block 256
__global__ __launch_bounds__(256) void s_kernel(
    const unsigned short* __restrict__ QKV1, const unsigned short* __restrict__ QKV2,
    float* __restrict__ S)
{
    const int bh = blockIdx.x, chunk = blockIdx.y;
    const int b = bh >> 3, h = bh & 7;
    __shared__ float Ks[8][64];
    __shared__ float Vs[8][64];
    const int tid = threadIdx.x;
    const int tx = tid & 15, ty = tid >> 4;
    float acc[4][4] = {};
    for (int pass = 0; pass < 2; ++pass) {
        const unsigned short* Qp = pass ? QKV2 : QKV1;
        for (int l0 = 0; l0 < 128; l0 += 8) {
#pragma unroll
            for (int it = 0; it < 2; ++it) {
                const int e = tid + it * 256;
                const int rr = e >> 6, cc = e & 63;
                const size_t row = (size_t)b * Lq + chunk * 128 + l0 + rr;
                Ks[rr][cc] = b2f(Qp[row * 1536 + 512 + h * 64 + cc]);
                Vs[rr][cc] = b2f(Qp[row * 1536 + 1024 + h * 64 + cc]);
            }
            __syncthreads();
#pragma unroll
            for (int rr = 0; rr < 8; ++rr) {
                float kv[4], vv[4];
#pragma unroll
                for (int i = 0; i < 4; ++i) kv[i] = Ks[rr][ty * 4 + i];
#pragma unroll
                for (int j = 0; j < 4; ++j) vv[j] = Vs[rr][tx * 4 + j];
#pragma unroll
                for (int i = 0; i < 4; ++i)
#pragma unroll
                    for (int j = 0; j < 4; ++j)
                        acc[i][j] = fmaf(kv[i], vv[j], acc[i][j]);
            }
            __syncthreads();
        }
    }
#pragma unroll
    for (int i = 0; i < 4; ++i)
#pragma unroll
        for (int j = 0; j < 4; ++j)
            atomicAdd(&S[((size_t)bh * 64 + ty * 4 + i) * 64 + tx * 4 + j], acc[i][j]);
}

// ------- attn = Q(bf16, in QKV stride 1536) @ S[b,h] -> bf16 [8192,512] -------
// grid (32 bh, 32 l-tiles of 64), block 256
__global__ __launch_bounds__(256) void attn_kernel(
    const unsigned short* __restrict__ QKV, const float* __restrict__ S,
    unsigned short* __restrict__ Ob)
{
    const int bh = blockIdx.x, lt = blockIdx.y;
    const int b = bh >> 3, h = bh & 7;
    __shared__ float Ss[64][65];
    __shared__ float Qs[64][65];
    const int tid = threadIdx.x;
    const int tx = tid & 15, ty = tid >> 4;
    const float* Sp = S + (size_t)bh * 4096;
#pragma unroll
    for (int it = 0; it < 16; ++it) {
        const int e = tid + it * 256;
        const int row = e >> 6, cc = e & 63;
        Ss[row][cc] = Sp[e];
        Qs[row][cc] = b2f(QKV[((size_t)b * Lq + lt * 64 + row) * 1536 + h * 64 + cc]);
    }
    __syncthreads();
    float acc[4][4] = {};
#pragma unroll
    for (int dk = 0; dk < 64; ++dk) {
        float qv[4], sv[4];
#pragma unroll
        for (int i = 0; i < 4; ++i) qv[i] = Qs[ty * 4 + i][dk];
#pragma unroll
        for (int j = 0; j < 4; ++j) sv[j] = Ss[dk][tx * 4 + j];
#pragma unroll
        for (int i = 0; i < 4; ++i)
#pragma unroll
            for (int j = 0; j < 4; ++j)
                acc[i][j] = fmaf(qv[i], sv[j], acc[i][j]);
    }
#pragma unroll
    for (int i = 0; i < 4; ++i)
#pragma unroll
        for (int j = 0; j < 4; ++j)
            Ob[((size_t)b * Lq + lt * 64 + ty * 4 + i) * 512 + h * 64 + tx * 4 + j] =
                f2b(acc[i][j]);
}

// ------- LayerNorm in place (fp32) + bf16 copy out -------
__global__ __launch_bounds__(256) void ln_make_bf16(
    float* __restrict__ X, const float* __restrict__ g, const float* __restrict__ bta,
    unsigned short* __restrict__ Xb)
{
    __shared__ float red[256];
    const int row = blockIdx.x;
    const int t = threadIdx.x;
    float* xr = X + (size_t)row * Dq;
    float v0 = xr[t], v1 = xr[t + 256];
    red[t] = v0 + v1;
    __syncthreads();
    for (int s = 128; s > 0; s >>= 1) { if (t < s) red[t] += red[t + s]; __syncthreads(); }
    const float mean = red[0] * (1.f / Dq);
    __syncthreads();
    const float d0 = v0 - mean, d1 = v1 - mean;
    red[t] = d0 * d0 + d1 * d1;
    __syncthreads();
    for (int s = 128; s > 0; s >>= 1) { if (t < s) red[t] += red[t + s]; __syncthreads(); }
    const float rstd = rsqrtf(red[0] * (1.f / Dq) + 1e-5f);
    const float y0 = d0 * rstd * g[t] + bta[t];
    const float y1 = d1 * rstd * g[t + 256] + bta[t + 256];
    xr[t] = y0;  xr[t + 256] = y1;
    unsigned short* xb = Xb + (size_t)row * Dq;
    xb[t] = f2b(y0);  xb[t + 256] = f2b(y1);
}

// ------- LayerNorm -> output half (row stride 1024) -------
__global__ __launch_bounds__(256) void ln_to_out(
    const float* __restrict__ Y, const float* __restrict__ g, const float* __restrict__ bta,
    float* __restrict__ out, int halfOff)
{
    __shared__ float red[256];
    const int row = blockIdx.x;
    const int t = threadIdx.x;
    const float* yr = Y + (size_t)row * Dq;
    float v0 = yr[t], v1 = yr[t + 256];
    red[t] = v0 + v1;
    __syncthreads();
    for (int s = 128; s > 0; s >>= 1) { if (t < s) red[t] += red[t + s]; __syncthreads(); }
    const float mean = red[0] * (1.f / Dq);
    __syncthreads();
    const float d0 = v0 - mean, d1 = v1 - mean;
    red[t] = d0 * d0 + d1 * d1;
    __syncthreads();
    for (int s = 128; s > 0; s >>= 1) { if (t < s) red[t] += red[t + s]; __syncthreads(); }
    const float rstd = rsqrtf(red[0] * (1.f / Dq) + 1e-5f);
    float* orow = out + (size_t)row * 1024 + halfOff;
    orow[t] = d0 * rstd * g[t] + bta[t];
    orow[t + 256] = d1 * rstd * g[t + 256] + bta[t + 256];
}

extern "C" void kernel_launch(void* const* d_in, const int* in_sizes, int n_in,
                              void* d_out, int out_size, void* d_ws, size_t ws_size,
                              hipStream_t stream)
{
    const float* question = (const float*)d_in[0];
    const float* query    = (const float*)d_in[1];
    const float* Wq = (const float*)d_in[2];  const float* bqp = (const float*)d_in[3];
    const float* Wk = (const float*)d_in[4];  const float* bkp = (const float*)d_in[5];
    const float* Wv = (const float*)d_in[6];  const float* bvp = (const float*)d_in[7];
    const float* Wo = (const float*)d_in[8];  const float* bo  = (const float*)d_in[9];
    const float* ln_g = (const float*)d_in[10]; const float* ln_b = (const float*)d_in[11];
    const float* W1 = (const float*)d_in[12]; const float* b1 = (const float*)d_in[13];
    const float* W2 = (const float*)d_in[14]; const float* b2 = (const float*)d_in[15];
    float* out = (float*)d_out;
    char* ws = (char*)d_ws;

    // ---- workspace layout (bytes) ----
    // [0,24M)   QKVb1 bf16 [8192,1536]  -> later x1 fp32 [8192,512] (16M)
    // [24,48M)  QKVb2 bf16              -> later x2 fp32
    // [48,56M)  attn1b bf16 [8192,512]  -> later x1b bf16
    // [56,64M)  attn2b bf16             -> later x2b bf16
    // [64,80M)  Xb1+Xb2 bf16 (8M each)  -> later h_b bf16 [4096,2048] (16M)
    // [80,80.5M) S fp32 [32,64,64]
    // [80.5M..) weights bf16 + bqkv fp32 (~6M)      total ~91 MiB
    unsigned short* QKVb1 = (unsigned short*)(ws);
    unsigned short* QKVb2 = (unsigned short*)(ws + 24 * MiBu);
    float* x1 = (float*)(ws);
    float* x2 = (float*)(ws + 24 * MiBu);
    unsigned short* attn1b = (unsigned short*)(ws + 48 * MiBu);
    unsigned short* attn2b = (unsigned short*)(ws + 56 * MiBu);
    unsigned short* x1b = attn1b;
    unsigned short* x2b = attn2b;
    unsigned short* Xb1 = (unsigned short*)(ws + 64 * MiBu);
    unsigned short* Xb2 = (unsigned short*)(ws + 72 * MiBu);
    unsigned short* hb  = (unsigned short*)(ws + 64 * MiBu);
    float* S = (float*)(ws + 80 * MiBu);
    char* wp = ws + 80 * MiBu + 524288;
    unsigned short* Wqkvb = (unsigned short*)wp;            wp += 1536 * 512 * 2;
    unsigned short* Wob   = (unsigned short*)wp;            wp += 512 * 512 * 2;
    unsigned short* W1b   = (unsigned short*)wp;            wp += 2048 * 512 * 2;
    unsigned short* W2b   = (unsigned short*)wp;            wp += 512 * 2048 * 2;
    float* bqkv           = (float*)wp;

    dim3 blk(256);

    // weight + input conversions
    convert_bf16<<<256, blk, 0, stream>>>(Wq, Wqkvb);
    convert_bf16<<<256, blk, 0, stream>>>(Wk, Wqkvb + 512 * 512);
    convert_bf16<<<256, blk, 0, stream>>>(Wv, Wqkvb + 1024 * 512);
    convert_bf16<<<256, blk, 0, stream>>>(Wo, Wob);
    convert_bf16<<<1024, blk, 0, stream>>>(W1, W1b);
    convert_bf16<<<1024, blk, 0, stream>>>(W2, W2b);
    build_bqkv<<<6, blk, 0, stream>>>(bqp, bkp, bvp, bqkv);
    zero_kernel<<<128, blk, 0, stream>>>(S);
    convert_bf16<<<4096, blk, 0, stream>>>(question, Xb1);
    convert_bf16<<<4096, blk, 0, stream>>>(query, Xb2);

    // fused QKV GEMMs: [8192,512] @ [1536,512]^T -> bf16 [8192,1536]
    gemm_bf16<<<dim3(12, 64), blk, 0, stream>>>(Xb1, Wqkvb, bqkv, nullptr, nullptr, QKVb1,
                                                Mrows, 1536, 512, 0);
    gemm_bf16<<<dim3(12, 64), blk, 0, stream>>>(Xb2, Wqkvb, bqkv, nullptr, nullptr, QKVb2,
                                                Mrows, 1536, 512, 0);

    // S then attn (both inputs share S)
    s_kernel<<<dim3(32, 16), blk, 0, stream>>>(QKVb1, QKVb2, S);
    attn_kernel<<<dim3(32, 32), blk, 0, stream>>>(QKVb1, S, attn1b);
    attn_kernel<<<dim3(32, 32), blk, 0, stream>>>(QKVb2, S, attn2b);

    // o-proj + residual -> x fp32 (overwrites QKV regions)
    gemm_bf16<<<dim3(4, 64), blk, 0, stream>>>(attn1b, Wob, bo, question, x1, nullptr,
                                               Mrows, 512, 512, 0);
    gemm_bf16<<<dim3(4, 64), blk, 0, stream>>>(attn2b, Wob, bo, query, x2, nullptr,
                                               Mrows, 512, 512, 0);

    // LN in place + bf16 copies (x1b overwrites attn1b after o-proj)
    ln_make_bf16<<<Mrows, blk, 0, stream>>>(x1, ln_g, ln_b, x1b);
    ln_make_bf16<<<Mrows, blk, 0, stream>>>(x2, ln_g, ln_b, x2b);

    // FFN, chunked by 4096 rows (h_b reuses Xb region, 16 MiB)
    for (int half = 0; half < 2; ++half) {
        float* x = half ? x2 : x1;
        unsigned short* xb = half ? x2b : x1b;
        for (int c = 0; c < 2; ++c) {
            const size_t roff = (size_t)c * 4096;
            // h = relu(x @ W1^T + b1) -> bf16 [4096,2048]
            gemm_bf16<<<dim3(16, 32), blk, 0, stream>>>(xb + roff * 512, W1b, b1, nullptr,
                                                        nullptr, hb, 4096, PFq, 512, 1);
            // y = h @ W2^T + b2 + x -> fp32 in place into x
            gemm_bf16<<<dim3(4, 32), blk, 0, stream>>>(hb, W2b, b2, x + roff * 512,
                                                       x + roff * 512, nullptr, 4096, 512, PFq, 0);
        }
        ln_to_out<<<Mrows, blk, 0, stream>>>(x, ln_g, ln_b, out, half * 512);
    }
}

// Round 3
// 579.036 us; speedup vs baseline: 4.0867x; 1.2104x over previous
//
#include <hip/hip_runtime.h>
#include <stdint.h>

// CrossAttention via linear-attention algebra:
//   S = K1^T V1 + K2^T V2 (per b,h; 64x64), shared by both outputs.
//   attn_i = Q_i @ S ; x = LN(inp + attn@Wo^T + bo) ; out = LN(x + FF(x))
// All big GEMMs bf16 MFMA (fp32 accum), m97 structure. Narrow-N GEMMs use
// split-K + fp32 atomicAdd so every dispatch has >=2 blocks/CU.

#define Bq 4
#define Lq 2048
#define Dq 512
#define PFq 2048
#define Mrows 8192
#define MiBu 1048576ull

typedef __attribute__((ext_vector_type(8))) short frag_ab;
typedef __attribute__((ext_vector_type(4))) float frag_cd;

__device__ __forceinline__ unsigned short f2b(float f) {
    union { float f; uint32_t u; } x; x.f = f;
    uint32_t r = x.u + 0x7fffu + ((x.u >> 16) & 1u);
    return (unsigned short)(r >> 16);
}
__device__ __forceinline__ float b2f(unsigned short u) {
    union { uint32_t u; float f; } x; x.u = ((uint32_t)u) << 16;
    return x.f;
}

#define GLD16(g, l)                                                              \
    __builtin_amdgcn_global_load_lds(                                            \
        (const __attribute__((address_space(1))) void*)(const void*)(g),         \
        (__attribute__((address_space(3))) void*)(void*)(l), 16, 0, 0)

// ---------- bf16 MFMA GEMM: out = A[M,K]b @ W[N,K]b^T + bias (+relu) ------
// grid (N/128, M/128), block 256 (4 waves, each 64x64 of the 128x128 tile)
__global__ __launch_bounds__(256) void gemm_bf16(
    const unsigned short* __restrict__ A, const unsigned short* __restrict__ Wt,
    const float* __restrict__ bias,
    float* __restrict__ outF, unsigned short* __restrict__ outB,
    int M, int N, int K, int relu)
{
    __shared__ __align__(16) unsigned short At[128 * 32];
    __shared__ __align__(16) unsigned short Bt[128 * 32];
    const int tid = threadIdx.x;
    const int lane = tid & 63;
    const int w = tid >> 6;
    const int wm = (w >> 1) * 64, wn = (w & 1) * 64;
    const int lr = lane & 15;
    const int quad = lane >> 4;
    const size_t bm = (size_t)blockIdx.y * 128, bn = (size_t)blockIdx.x * 128;

    frag_cd acc[4][4] = {};

    const int e = tid * 8;
    const int ar = e >> 5, ac = e & 31;
    const unsigned short* Ag  = A  + (bm + ar) * (size_t)K + ac;
    const unsigned short* Bg  = Wt + (bn + ar) * (size_t)K + ac;
    const unsigned short* Ag2 = Ag + (size_t)64 * K;
    const unsigned short* Bg2 = Bg + (size_t)64 * K;
    unsigned short* Asd = At + w * 512;
    unsigned short* Bsd = Bt + w * 512;

    for (int k0 = 0; k0 < K; k0 += 32) {
        __syncthreads();
        GLD16(Ag  + k0, Asd);
        GLD16(Ag2 + k0, Asd + 2048);
        GLD16(Bg  + k0, Bsd);
        GLD16(Bg2 + k0, Bsd + 2048);
        __syncthreads();
        frag_ab a[4], b[4];
#pragma unroll
        for (int i = 0; i < 4; ++i)
            a[i] = *(const frag_ab*)&At[(wm + i * 16 + lr) * 32 + quad * 8];
#pragma unroll
        for (int j = 0; j < 4; ++j)
            b[j] = *(const frag_ab*)&Bt[(wn + j * 16 + lr) * 32 + quad * 8];
#pragma unroll
        for (int i = 0; i < 4; ++i)
#pragma unroll
            for (int j = 0; j < 4; ++j)
                acc[i][j] = __builtin_amdgcn_mfma_f32_16x16x32_bf16(a[i], b[j], acc[i][j], 0, 0, 0);
    }

#pragma unroll
    for (int j = 0; j < 4; ++j) {
        const int col = (int)bn + wn + j * 16 + lr;
        const float bv = bias[col];
#pragma unroll
        for (int i = 0; i < 4; ++i) {
            const int rowb = (int)bm + wm + i * 16 + quad * 4;
#pragma unroll
            for (int r = 0; r < 4; ++r) {
                float v = acc[i][j][r] + bv;
                const size_t idx = (size_t)(rowb + r) * N + col;
                if (relu) v = fmaxf(v, 0.f);
                if (outF) outF[idx] = v;
                if (outB) outB[idx] = f2b(v);
            }
        }
    }
}

// ---------- split-K variant: atomicAdd partial A@W^T into fp32 out ----------
// grid (N/128, M/128, nsplit); K-range [z*Kc, (z+1)*Kc); no bias (folded later)
__global__ __launch_bounds__(256) void gemm_bf16_splitk(
    const unsigned short* __restrict__ A, const unsigned short* __restrict__ Wt,
    float* __restrict__ outAcc, int M, int N, int Ktot, int Kc)
{
    __shared__ __align__(16) unsigned short At[128 * 32];
    __shared__ __align__(16) unsigned short Bt[128 * 32];
    const int tid = threadIdx.x;
    const int lane = tid & 63;
    const int w = tid >> 6;
    const int wm = (w >> 1) * 64, wn = (w & 1) * 64;
    const int lr = lane & 15;
    const int quad = lane >> 4;
    const size_t bm = (size_t)blockIdx.y * 128, bn = (size_t)blockIdx.x * 128;
    const int kbase = blockIdx.z * Kc;

    frag_cd acc[4][4] = {};

    const int e = tid * 8;
    const int ar = e >> 5, ac = e & 31;
    const unsigned short* Ag  = A  + (bm + ar) * (size_t)Ktot + ac;
    const unsigned short* Bg  = Wt + (bn + ar) * (size_t)Ktot + ac;
    const unsigned short* Ag2 = Ag + (size_t)64 * Ktot;
    const unsigned short* Bg2 = Bg + (size_t)64 * Ktot;
    unsigned short* Asd = At + w * 512;
    unsigned short* Bsd = Bt + w * 512;

    for (int k0 = kbase; k0 < kbase + Kc; k0 += 32) {
        __syncthreads();
        GLD16(Ag  + k0, Asd);
        GLD16(Ag2 + k0, Asd + 2048);
        GLD16(Bg  + k0, Bsd);
        GLD16(Bg2 + k0, Bsd + 2048);
        __syncthreads();
        frag_ab a[4], b[4];
#pragma unroll
        for (int i = 0; i < 4; ++i)
            a[i] = *(const frag_ab*)&At[(wm + i * 16 + lr) * 32 + quad * 8];
#pragma unroll
        for (int j = 0; j < 4; ++j)
            b[j] = *(const frag_ab*)&Bt[(wn + j * 16 + lr) * 32 + quad * 8];
#pragma unroll
        for (int i = 0; i < 4; ++i)
#pragma unroll
            for (int j = 0; j < 4; ++j)
                acc[i][j] = __builtin_amdgcn_mfma_f32_16x16x32_bf16(a[i], b[j], acc[i][j], 0, 0, 0);
    }

#pragma unroll
    for (int j = 0; j < 4; ++j) {
        const int col = (int)bn + wn + j * 16 + lr;
#pragma unroll
        for (int i = 0; i < 4; ++i) {
            const int rowb = (int)bm + wm + i * 16 + quad * 4;
#pragma unroll
            for (int r = 0; r < 4; ++r)
                atomicAdd(outAcc + (size_t)(rowb + r) * N + col, acc[i][j][r]);
        }
    }
}

// ---------------- merged fp32->bf16 converts + S zero ----------------
__global__ __launch_bounds__(256) void convert_all(
    const float* __restrict__ Wq, const float* __restrict__ Wk,
    const float* __restrict__ Wv, const float* __restrict__ Wo,
    const float* __restrict__ W1, const float* __restrict__ W2,
    const float* __restrict__ question, const float* __restrict__ query,
    unsigned short* __restrict__ Wqkvb, unsigned short* __restrict__ Wob,
    unsigned short* __restrict__ W1b, unsigned short* __restrict__ W2b,
    unsigned short* __restrict__ Xb1, unsigned short* __restrict__ Xb2,
    float* __restrict__ S)
{
    const int b = blockIdx.x;
    const float* src; unsigned short* dst; size_t off;
    if (b < 256)        { src = Wq; dst = Wqkvb;          off = (size_t)b * 1024; }
    else if (b < 512)   { src = Wk; dst = Wqkvb + 262144; off = (size_t)(b - 256) * 1024; }
    else if (b < 768)   { src = Wv; dst = Wqkvb + 524288; off = (size_t)(b - 512) * 1024; }
    else if (b < 1024)  { src = Wo; dst = Wob;            off = (size_t)(b - 768) * 1024; }
    else if (b < 2048)  { src = W1; dst = W1b;            off = (size_t)(b - 1024) * 1024; }
    else if (b < 3072)  { src = W2; dst = W2b;            off = (size_t)(b - 2048) * 1024; }
    else if (b < 7168)  { src = question; dst = Xb1;      off = (size_t)(b - 3072) * 1024; }
    else if (b < 11264) { src = query; dst = Xb2;         off = (size_t)(b - 7168) * 1024; }
    else {  // zero S: 128 blocks x 1024 floats
        const size_t idx = ((size_t)(b - 11264) * 256 + threadIdx.x) * 4;
        *(float4*)(S + idx) = make_float4(0.f, 0.f, 0.f, 0.f);
        return;
    }
    const size_t idx = off + threadIdx.x * 4;
    float4 v = *(const float4*)(src + idx);
    ushort4 o;
    o.x = f2b(v.x); o.y = f2b(v.y); o.z = f2b(v.z); o.w = f2b(v.w);
    *(ushort4*)(dst + idx) = o;
}

// ---------------- build concatenated QKV bias ----------------
__global__ __launch_bounds__(256) void build_bqkv(
    const float* __restrict__ bqp, const float* __restrict__ bkp,
    const float* __restrict__ bvp, float* __restrict__ bqkv)
{
    const int n = blockIdx.x * 256 + threadIdx.x;
    float v = (n < 512) ? bqp[n] : (n < 1024) ? bkp[n - 512] : bvp[n - 1024];
    bqkv[n] = v;
}

// ------- S[b,h] += K1^T V1 + K2^T V2 (bf16 K/V in QKV buffers, stride 1536) ----
__global__ __launch_bounds__(256) void s_kernel(
    const unsigned short* __restrict__ QKV1, const unsigned short* __restrict__ QKV2,
    float* __restrict__ S)
{
    const int bh = blockIdx.x, chunk = blockIdx.y;
    const int b = bh >> 3, h = bh & 7;
    __shared__ float Ks[8][64];
    __shared__ float Vs[8][64];
    const int tid = threadIdx.x;
    const int tx = tid & 15, ty = tid >> 4;
    float acc[4][4] = {};
    for (int pass = 0; pass < 2; ++pass) {
        const unsigned short* Qp = pass ? QKV2 : QKV1;
        for (int l0 = 0; l0 < 128; l0 += 8) {
#pragma unroll
            for (int it = 0; it < 2; ++it) {
                const int e = tid + it * 256;
                const int rr = e >> 6, cc = e & 63;
                const size_t row = (size_t)b * Lq + chunk * 128 + l0 + rr;
                Ks[rr][cc] = b2f(Qp[row * 1536 + 512 + h * 64 + cc]);
                Vs[rr][cc] = b2f(Qp[row * 1536 + 1024 + h * 64 + cc]);
            }
            __syncthreads();
#pragma unroll
            for (int rr = 0; rr < 8; ++rr) {
                float kv[4], vv[4];
#pragma unroll
                for (int i = 0; i < 4; ++i) kv[i] = Ks[rr][ty * 4 + i];
#pragma unroll
                for (int j = 0; j < 4; ++j) vv[j] = Vs[rr][tx * 4 + j];
#pragma unroll
                for (int i = 0; i < 4; ++i)
#pragma unroll
                    for (int j = 0; j < 4; ++j)
                        acc[i][j] = fmaf(kv[i], vv[j], acc[i][j]);
            }
            __syncthreads();
        }
    }
#pragma unroll
    for (int i = 0; i < 4; ++i)
#pragma unroll
        for (int j = 0; j < 4; ++j)
            atomicAdd(&S[((size_t)bh * 64 + ty * 4 + i) * 64 + tx * 4 + j], acc[i][j]);
}

// ------- S fp32 -> Sbt bf16, B-operand layout [bh][khalf][n][kj] -------
// Sbt[bh][kk][n][kj] = S[bh][kk*32+kj][n]; grid 32, block 256, 16 elems/thread
__global__ __launch_bounds__(256) void sbt_convert(
    const float* __restrict__ S, unsigned short* __restrict__ Sbt)
{
    const int bh = blockIdx.x;
    const float* Sp = S + (size_t)bh * 4096;
    unsigned short* Dp = Sbt + (size_t)bh * 4096;
    const int t = threadIdx.x;
#pragma unroll
    for (int u = 0; u < 16; ++u) {
        const int d = t * 16 + u;
        const int kj = d & 31, n = (d >> 5) & 63, kk = d >> 11;
        Dp[d] = f2b(Sp[(size_t)(kk * 32 + kj) * 64 + n]);
    }
}

// ------- attn = Q @ S_bh via MFMA; block: 128 rows x 64 cols (one head) -------
// grid (8 heads, 64 row-tiles); Q from QKV (stride 1536), Sbt bf16, out bf16
__global__ __launch_bounds__(256) void attn_mfma(
    const unsigned short* __restrict__ QKV, const unsigned short* __restrict__ Sbt,
    unsigned short* __restrict__ Ob)
{
    __shared__ __align__(16) unsigned short At[2 * 128 * 32];  // [kk][row][32]
    __shared__ __align__(16) unsigned short Bt[2 * 64 * 32];   // [kk][n][32]
    const int h = blockIdx.x;
    const int rt = blockIdx.y;
    const int rbase = rt * 128;
    const int b = rbase >> 11;           // rbase / 2048
    const int bh = b * 8 + h;
    const int tid = threadIdx.x;
    const int lane = tid & 63;
    const int w = tid >> 6;
    const int lr = lane & 15;
    const int quad = lane >> 4;

    // stage A: 4 issues; it -> (kk = it&1, rowhalf = it>>1)
    {
        const int rloc = tid >> 2, c8 = (tid & 3) * 8;
#pragma unroll
        for (int it = 0; it < 4; ++it) {
            const int kk = it & 1, rh = it >> 1;
            const unsigned short* g = QKV +
                ((size_t)rbase + rh * 64 + rloc) * 1536 + h * 64 + kk * 32 + c8;
            unsigned short* l = At + kk * 4096 + rh * 2048 + w * 512;
            GLD16(g, l);
        }
        // stage B: 2 issues, contiguous copy of Sbt[bh]
        const unsigned short* Sg = Sbt + (size_t)bh * 4096 + tid * 8;
#pragma unroll
        for (int bi = 0; bi < 2; ++bi)
            GLD16(Sg + bi * 2048, Bt + bi * 2048 + w * 512);
    }
    __syncthreads();

    frag_cd acc[2][4] = {};
#pragma unroll
    for (int kk = 0; kk < 2; ++kk) {
        frag_ab a[2], bfr[4];
#pragma unroll
        for (int i = 0; i < 2; ++i)
            a[i] = *(const frag_ab*)&At[kk * 4096 + (w * 32 + i * 16 + lr) * 32 + quad * 8];
#pragma unroll
        for (int j = 0; j < 4; ++j)
            bfr[j] = *(const frag_ab*)&Bt[kk * 2048 + (j * 16 + lr) * 32 + quad * 8];
#pragma unroll
        for (int i = 0; i < 2; ++i)
#pragma unroll
            for (int j = 0; j < 4; ++j)
                acc[i][j] = __builtin_amdgcn_mfma_f32_16x16x32_bf16(a[i], bfr[j], acc[i][j], 0, 0, 0);
    }

#pragma unroll
    for (int i = 0; i < 2; ++i) {
        const int rowb = rbase + w * 32 + i * 16 + quad * 4;
#pragma unroll
        for (int j = 0; j < 4; ++j) {
            const int col = h * 64 + j * 16 + lr;
#pragma unroll
            for (int r = 0; r < 4; ++r)
                Ob[(size_t)(rowb + r) * 512 + col] = f2b(acc[i][j][r]);
        }
    }
}

// ------- LayerNorm of (x + bo) in place (fp32) + bf16 copy out -------
__global__ __launch_bounds__(256) void ln_make_bf16(
    float* __restrict__ X, const float* __restrict__ g, const float* __restrict__ bta,
    const float* __restrict__ badd, unsigned short* __restrict__ Xb)
{
    __shared__ float red[256];
    const int row = blockIdx.x;
    const int t = threadIdx.x;
    float* xr = X + (size_t)row * Dq;
    float v0 = xr[t] + badd[t], v1 = xr[t + 256] + badd[t + 256];
    red[t] = v0 + v1;
    __syncthreads();
    for (int s = 128; s > 0; s >>= 1) { if (t < s) red[t] += red[t + s]; __syncthreads(); }
    const float mean = red[0] * (1.f / Dq);
    __syncthreads();
    const float d0 = v0 - mean, d1 = v1 - mean;
    red[t] = d0 * d0 + d1 * d1;
    __syncthreads();
    for (int s = 128; s > 0; s >>= 1) { if (t < s) red[t] += red[t + s]; __syncthreads(); }
    const float rstd = rsqrtf(red[0] * (1.f / Dq) + 1e-5f);
    const float y0 = d0 * rstd * g[t] + bta[t];
    const float y1 = d1 * rstd * g[t + 256] + bta[t + 256];
    xr[t] = y0;  xr[t + 256] = y1;
    unsigned short* xb = Xb + (size_t)row * Dq;
    xb[t] = f2b(y0);  xb[t + 256] = f2b(y1);
}

// ------- LayerNorm of (y + b2) -> output half (row stride 1024) -------
__global__ __launch_bounds__(256) void ln_to_out(
    const float* __restrict__ Y, const float* __restrict__ g, const float* __restrict__ bta,
    const float* __restrict__ badd, float* __restrict__ out, int halfOff)
{
    __shared__ float red[256];
    const int row = blockIdx.x;
    const int t = threadIdx.x;
    const float* yr = Y + (size_t)row * Dq;
    float v0 = yr[t] + badd[t], v1 = yr[t + 256] + badd[t + 256];
    red[t] = v0 + v1;
    __syncthreads();
    for (int s = 128; s > 0; s >>= 1) { if (t < s) red[t] += red[t + s]; __syncthreads(); }
    const float mean = red[0] * (1.f / Dq);
    __syncthreads();
    const float d0 = v0 - mean, d1 = v1 - mean;
    red[t] = d0 * d0 + d1 * d1;
    __syncthreads();
    for (int s = 128; s > 0; s >>= 1) { if (t < s) red[t] += red[t + s]; __syncthreads(); }
    const float rstd = rsqrtf(red[0] * (1.f / Dq) + 1e-5f);
    float* orow = out + (size_t)row * 1024 + halfOff;
    orow[t] = d0 * rstd * g[t] + bta[t];
    orow[t + 256] = d1 * rstd * g[t + 256] + bta[t + 256];
}

extern "C" void kernel_launch(void* const* d_in, const int* in_sizes, int n_in,
                              void* d_out, int out_size, void* d_ws, size_t ws_size,
                              hipStream_t stream)
{
    const float* question = (const float*)d_in[0];
    const float* query    = (const float*)d_in[1];
    const float* Wq = (const float*)d_in[2];  const float* bqp = (const float*)d_in[3];
    const float* Wk = (const float*)d_in[4];  const float* bkp = (const float*)d_in[5];
    const float* Wv = (const float*)d_in[6];  const float* bvp = (const float*)d_in[7];
    const float* Wo = (const float*)d_in[8];  const float* bo  = (const float*)d_in[9];
    const float* ln_g = (const float*)d_in[10]; const float* ln_b = (const float*)d_in[11];
    const float* W1 = (const float*)d_in[12]; const float* b1 = (const float*)d_in[13];
    const float* W2 = (const float*)d_in[14]; const float* b2 = (const float*)d_in[15];
    float* out = (float*)d_out;
    char* ws = (char*)d_ws;

    // ---- workspace layout (bytes), total ~87 MiB ----
    // phase A: QKVb1 [0,24M) QKVb2 [24,48M) attn1b [48,56M) attn2b [56,64M)
    //          Xb1 [64,72M) Xb2 [72,80M)
    // phase B: x1 f32 [0,16M) x2 f32 [16,32M) x1b [32,40M) x2b [40,48M)
    //          h bf16 [48,80M)
    // fixed:   S f32 [80M,80.5M) then weights bf16 + Sbt + bqkv
    unsigned short* QKVb1 = (unsigned short*)(ws);
    unsigned short* QKVb2 = (unsigned short*)(ws + 24 * MiBu);
    unsigned short* attn1b = (unsigned short*)(ws + 48 * MiBu);
    unsigned short* attn2b = (unsigned short*)(ws + 56 * MiBu);
    unsigned short* Xb1 = (unsigned short*)(ws + 64 * MiBu);
    unsigned short* Xb2 = (unsigned short*)(ws + 72 * MiBu);
    float* x1 = (float*)(ws);
    float* x2 = (float*)(ws + 16 * MiBu);
    unsigned short* x1b = (unsigned short*)(ws + 32 * MiBu);
    unsigned short* x2b = (unsigned short*)(ws + 40 * MiBu);
    unsigned short* hb  = (unsigned short*)(ws + 48 * MiBu);
    float* S = (float*)(ws + 80 * MiBu);
    char* wp = ws + 80 * MiBu + 524288;
    unsigned short* Wqkvb = (unsigned short*)wp;  wp += 1536 * 512 * 2;
    unsigned short* Wob   = (unsigned short*)wp;  wp += 512 * 512 * 2;
    unsigned short* W1b   = (unsigned short*)wp;  wp += 2048 * 512 * 2;
    unsigned short* W2b   = (unsigned short*)wp;  wp += 512 * 2048 * 2;
    unsigned short* Sbt   = (unsigned short*)wp;  wp += 32 * 4096 * 2;
    float* bqkv           = (float*)wp;

    dim3 blk(256);

    // conversions (+ S zero) and QKV bias concat
    convert_all<<<11392, blk, 0, stream>>>(Wq, Wk, Wv, Wo, W1, W2, question, query,
                                           Wqkvb, Wob, W1b, W2b, Xb1, Xb2, S);
    build_bqkv<<<6, blk, 0, stream>>>(bqp, bkp, bvp, bqkv);

    // fused QKV GEMMs: [8192,512] @ [1536,512]^T -> bf16 [8192,1536]
    gemm_bf16<<<dim3(12, 64), blk, 0, stream>>>(Xb1, Wqkvb, bqkv, nullptr, QKVb1,
                                                Mrows, 1536, 512, 0);
    gemm_bf16<<<dim3(12, 64), blk, 0, stream>>>(Xb2, Wqkvb, bqkv, nullptr, QKVb2,
                                                Mrows, 1536, 512, 0);

    // S (fp32 accum) -> bf16 transposed; then attn via MFMA
    s_kernel<<<dim3(32, 16), blk, 0, stream>>>(QKVb1, QKVb2, S);
    sbt_convert<<<32, blk, 0, stream>>>(S, Sbt);
    attn_mfma<<<dim3(8, 64), blk, 0, stream>>>(QKVb1, Sbt, attn1b);
    attn_mfma<<<dim3(8, 64), blk, 0, stream>>>(QKVb2, Sbt, attn2b);

    // residual preload, then o-proj split-K=2 atomic-accumulated into x
    hipMemcpyAsync(x1, question, (size_t)Mrows * Dq * 4, hipMemcpyDeviceToDevice, stream);
    hipMemcpyAsync(x2, query,    (size_t)Mrows * Dq * 4, hipMemcpyDeviceToDevice, stream);
    gemm_bf16_splitk<<<dim3(4, 64, 2), blk, 0, stream>>>(attn1b, Wob, x1, Mrows, 512, 512, 256);
    gemm_bf16_splitk<<<dim3(4, 64, 2), blk, 0, stream>>>(attn2b, Wob, x2, Mrows, 512, 512, 256);

    // LN(x + bo) in place + bf16 copies
    ln_make_bf16<<<Mrows, blk, 0, stream>>>(x1, ln_g, ln_b, bo, x1b);
    ln_make_bf16<<<Mrows, blk, 0, stream>>>(x2, ln_g, ln_b, bo, x2b);

    // FFN full-M per half; FFN2 split-K=4 accumulates onto x (residual in place)
    for (int half = 0; half < 2; ++half) {
        float* x = half ? x2 : x1;
        unsigned short* xb = half ? x2b : x1b;
        gemm_bf16<<<dim3(16, 64), blk, 0, stream>>>(xb, W1b, b1, nullptr, hb,
                                                    Mrows, PFq, 512, 1);
        gemm_bf16_splitk<<<dim3(4, 64, 4), blk, 0, stream>>>(hb, W2b, x, Mrows, 512, PFq, 512);
        ln_to_out<<<Mrows, blk, 0, stream>>>(x, ln_g, ln_b, b2, out, half * 512);
    }
}

// Round 4
// 434.431 us; speedup vs baseline: 5.4470x; 1.3329x over previous
//
#include <hip/hip_runtime.h>
#include <stdint.h>

// CrossAttention via linear-attention algebra, both halves merged to M=16384:
//   S = K1^T V1 + K2^T V2 (per b,h; 64x64), shared by both halves.
//   attn = Q @ S ; x = LN(inp + attn@Wo^T + bo) ; out = LN(x + FF(x))
// All GEMMs bf16 MFMA (fp32 accum), m97 structure (128x128 tile, BK=32,
// global_load_lds width=16). FFN2 uses deterministic split-K=2 partials
// (plain stores), reduced inside the final LayerNorm. No atomics on hot paths.

#define Bq 4
#define Lq 2048
#define Dq 512
#define PFq 2048
#define Mrows 16384           // merged: rows 0-8191 question, 8192-16383 query
#define MiBu 1048576ull

typedef __attribute__((ext_vector_type(8))) short frag_ab;
typedef __attribute__((ext_vector_type(4))) float frag_cd;

__device__ __forceinline__ unsigned short f2b(float f) {
    union { float f; uint32_t u; } x; x.f = f;
    uint32_t r = x.u + 0x7fffu + ((x.u >> 16) & 1u);
    return (unsigned short)(r >> 16);
}
__device__ __forceinline__ float b2f(unsigned short u) {
    union { uint32_t u; float f; } x; x.u = ((uint32_t)u) << 16;
    return x.f;
}

#define GLD16(g, l)                                                              \
    __builtin_amdgcn_global_load_lds(                                            \
        (const __attribute__((address_space(1))) void*)(const void*)(g),         \
        (__attribute__((address_space(3))) void*)(void*)(l), 16, 0, 0)

// ---------- bf16 MFMA GEMM: out = A[M,K]b @ W[N,K]b^T (+bias)(+relu) ----------
// grid (N/128, M/128), block 256 (4 waves, each 64x64 of the 128x128 tile)
__global__ __launch_bounds__(256) void gemm_bf16(
    const unsigned short* __restrict__ A, const unsigned short* __restrict__ Wt,
    const float* __restrict__ bias,
    float* __restrict__ outF, unsigned short* __restrict__ outB,
    int M, int N, int K, int relu)
{
    __shared__ __align__(16) unsigned short At[128 * 32];
    __shared__ __align__(16) unsigned short Bt[128 * 32];
    const int tid = threadIdx.x;
    const int lane = tid & 63;
    const int w = tid >> 6;
    const int wm = (w >> 1) * 64, wn = (w & 1) * 64;
    const int lr = lane & 15;
    const int quad = lane >> 4;
    const size_t bm = (size_t)blockIdx.y * 128, bn = (size_t)blockIdx.x * 128;

    frag_cd acc[4][4] = {};

    const int e = tid * 8;
    const int ar = e >> 5, ac = e & 31;
    const unsigned short* Ag  = A  + (bm + ar) * (size_t)K + ac;
    const unsigned short* Bg  = Wt + (bn + ar) * (size_t)K + ac;
    const unsigned short* Ag2 = Ag + (size_t)64 * K;
    const unsigned short* Bg2 = Bg + (size_t)64 * K;
    unsigned short* Asd = At + w * 512;
    unsigned short* Bsd = Bt + w * 512;

    for (int k0 = 0; k0 < K; k0 += 32) {
        __syncthreads();
        GLD16(Ag  + k0, Asd);
        GLD16(Ag2 + k0, Asd + 2048);
        GLD16(Bg  + k0, Bsd);
        GLD16(Bg2 + k0, Bsd + 2048);
        __syncthreads();
        frag_ab a[4], b[4];
#pragma unroll
        for (int i = 0; i < 4; ++i)
            a[i] = *(const frag_ab*)&At[(wm + i * 16 + lr) * 32 + quad * 8];
#pragma unroll
        for (int j = 0; j < 4; ++j)
            b[j] = *(const frag_ab*)&Bt[(wn + j * 16 + lr) * 32 + quad * 8];
#pragma unroll
        for (int i = 0; i < 4; ++i)
#pragma unroll
            for (int j = 0; j < 4; ++j)
                acc[i][j] = __builtin_amdgcn_mfma_f32_16x16x32_bf16(a[i], b[j], acc[i][j], 0, 0, 0);
    }

#pragma unroll
    for (int j = 0; j < 4; ++j) {
        const int col = (int)bn + wn + j * 16 + lr;
        const float bv = bias ? bias[col] : 0.f;
#pragma unroll
        for (int i = 0; i < 4; ++i) {
            const int rowb = (int)bm + wm + i * 16 + quad * 4;
#pragma unroll
            for (int r = 0; r < 4; ++r) {
                float v = acc[i][j][r] + bv;
                const size_t idx = (size_t)(rowb + r) * N + col;
                if (relu) v = fmaxf(v, 0.f);
                if (outF) outF[idx] = v;
                if (outB) outB[idx] = f2b(v);
            }
        }
    }
}

// ---------- split-K partial GEMM: p[z] = A@W^T over K-range, plain stores -----
// grid (N/128, M/128, 2); partial z at outP + z*pstride
__global__ __launch_bounds__(256) void gemm_bf16_partk(
    const unsigned short* __restrict__ A, const unsigned short* __restrict__ Wt,
    float* __restrict__ outP, size_t pstride, int M, int N, int Ktot, int Kc)
{
    __shared__ __align__(16) unsigned short At[128 * 32];
    __shared__ __align__(16) unsigned short Bt[128 * 32];
    const int tid = threadIdx.x;
    const int lane = tid & 63;
    const int w = tid >> 6;
    const int wm = (w >> 1) * 64, wn = (w & 1) * 64;
    const int lr = lane & 15;
    const int quad = lane >> 4;
    const size_t bm = (size_t)blockIdx.y * 128, bn = (size_t)blockIdx.x * 128;
    const int kbase = blockIdx.z * Kc;
    float* outp = outP + (size_t)blockIdx.z * pstride;

    frag_cd acc[4][4] = {};

    const int e = tid * 8;
    const int ar = e >> 5, ac = e & 31;
    const unsigned short* Ag  = A  + (bm + ar) * (size_t)Ktot + ac;
    const unsigned short* Bg  = Wt + (bn + ar) * (size_t)Ktot + ac;
    const unsigned short* Ag2 = Ag + (size_t)64 * Ktot;
    const unsigned short* Bg2 = Bg + (size_t)64 * Ktot;
    unsigned short* Asd = At + w * 512;
    unsigned short* Bsd = Bt + w * 512;

    for (int k0 = kbase; k0 < kbase + Kc; k0 += 32) {
        __syncthreads();
        GLD16(Ag  + k0, Asd);
        GLD16(Ag2 + k0, Asd + 2048);
        GLD16(Bg  + k0, Bsd);
        GLD16(Bg2 + k0, Bsd + 2048);
        __syncthreads();
        frag_ab a[4], b[4];
#pragma unroll
        for (int i = 0; i < 4; ++i)
            a[i] = *(const frag_ab*)&At[(wm + i * 16 + lr) * 32 + quad * 8];
#pragma unroll
        for (int j = 0; j < 4; ++j)
            b[j] = *(const frag_ab*)&Bt[(wn + j * 16 + lr) * 32 + quad * 8];
#pragma unroll
        for (int i = 0; i < 4; ++i)
#pragma unroll
            for (int j = 0; j < 4; ++j)
                acc[i][j] = __builtin_amdgcn_mfma_f32_16x16x32_bf16(a[i], b[j], acc[i][j], 0, 0, 0);
    }

#pragma unroll
    for (int j = 0; j < 4; ++j) {
        const int col = (int)bn + wn + j * 16 + lr;
#pragma unroll
        for (int i = 0; i < 4; ++i) {
            const int rowb = (int)bm + wm + i * 16 + quad * 4;
#pragma unroll
            for (int r = 0; r < 4; ++r)
                outp[(size_t)(rowb + r) * N + col] = acc[i][j][r];
        }
    }
}

// -------- merged fp32->bf16 converts + S zero + QKV bias concat --------
__global__ __launch_bounds__(256) void convert_all(
    const float* __restrict__ Wq, const float* __restrict__ Wk,
    const float* __restrict__ Wv, const float* __restrict__ Wo,
    const float* __restrict__ W1, const float* __restrict__ W2,
    const float* __restrict__ question, const float* __restrict__ query,
    const float* __restrict__ bqp, const float* __restrict__ bkp,
    const float* __restrict__ bvp,
    unsigned short* __restrict__ Wqkvb, unsigned short* __restrict__ Wob,
    unsigned short* __restrict__ W1b, unsigned short* __restrict__ W2b,
    unsigned short* __restrict__ Xb, float* __restrict__ S,
    float* __restrict__ bqkv)
{
    const int b = blockIdx.x;
    const float* src; unsigned short* dst; size_t off;
    if (b < 256)        { src = Wq; dst = Wqkvb;          off = (size_t)b * 1024; }
    else if (b < 512)   { src = Wk; dst = Wqkvb + 262144; off = (size_t)(b - 256) * 1024; }
    else if (b < 768)   { src = Wv; dst = Wqkvb + 524288; off = (size_t)(b - 512) * 1024; }
    else if (b < 1024)  { src = Wo; dst = Wob;            off = (size_t)(b - 768) * 1024; }
    else if (b < 2048)  { src = W1; dst = W1b;            off = (size_t)(b - 1024) * 1024; }
    else if (b < 3072)  { src = W2; dst = W2b;            off = (size_t)(b - 2048) * 1024; }
    else if (b < 7168)  { src = question; dst = Xb;       off = (size_t)(b - 3072) * 1024; }
    else if (b < 11264) { src = query; dst = Xb + 4194304; off = (size_t)(b - 7168) * 1024; }
    else if (b < 11392) {  // zero S: 128 blocks x 1024 floats
        const size_t idx = ((size_t)(b - 11264) * 256 + threadIdx.x) * 4;
        *(float4*)(S + idx) = make_float4(0.f, 0.f, 0.f, 0.f);
        return;
    } else {               // bqkv concat: 6 blocks
        const int n = (b - 11392) * 256 + threadIdx.x;
        bqkv[n] = (n < 512) ? bqp[n] : (n < 1024) ? bkp[n - 512] : bvp[n - 1024];
        return;
    }
    const size_t idx = off + threadIdx.x * 4;
    float4 v = *(const float4*)(src + idx);
    ushort4 o;
    o.x = f2b(v.x); o.y = f2b(v.y); o.z = f2b(v.z); o.w = f2b(v.w);
    *(ushort4*)(dst + idx) = o;
}

// ------- S[b,h] += sum over both halves of K^T outer V (merged QKV) -------
// grid (32 bh, 16 chunks), block 256
__global__ __launch_bounds__(256) void s_kernel(
    const unsigned short* __restrict__ QKV, float* __restrict__ S)
{
    const int bh = blockIdx.x, chunk = blockIdx.y;
    const int b = bh >> 3, h = bh & 7;
    __shared__ float Ks[8][64];
    __shared__ float Vs[8][64];
    const int tid = threadIdx.x;
    const int tx = tid & 15, ty = tid >> 4;
    float acc[4][4] = {};
    for (int pass = 0; pass < 2; ++pass) {
        for (int l0 = 0; l0 < 128; l0 += 8) {
#pragma unroll
            for (int it = 0; it < 2; ++it) {
                const int e = tid + it * 256;
                const int rr = e >> 6, cc = e & 63;
                const size_t row = (size_t)pass * 8192 + (size_t)b * Lq + chunk * 128 + l0 + rr;
                Ks[rr][cc] = b2f(QKV[row * 1536 + 512 + h * 64 + cc]);
                Vs[rr][cc] = b2f(QKV[row * 1536 + 1024 + h * 64 + cc]);
            }
            __syncthreads();
#pragma unroll
            for (int rr = 0; rr < 8; ++rr) {
                float kv[4], vv[4];
#pragma unroll
                for (int i = 0; i < 4; ++i) kv[i] = Ks[rr][ty * 4 + i];
#pragma unroll
                for (int j = 0; j < 4; ++j) vv[j] = Vs[rr][tx * 4 + j];
#pragma unroll
                for (int i = 0; i < 4; ++i)
#pragma unroll
                    for (int j = 0; j < 4; ++j)
                        acc[i][j] = fmaf(kv[i], vv[j], acc[i][j]);
            }
            __syncthreads();
        }
    }
#pragma unroll
    for (int i = 0; i < 4; ++i)
#pragma unroll
        for (int j = 0; j < 4; ++j)
            atomicAdd(&S[((size_t)bh * 64 + ty * 4 + i) * 64 + tx * 4 + j], acc[i][j]);
}

// ------- S fp32 -> Sbt bf16, B-operand layout [bh][khalf][n][kj] -------
__global__ __launch_bounds__(256) void sbt_convert(
    const float* __restrict__ S, unsigned short* __restrict__ Sbt)
{
    const int bh = blockIdx.x;
    const float* Sp = S + (size_t)bh * 4096;
    unsigned short* Dp = Sbt + (size_t)bh * 4096;
    const int t = threadIdx.x;
#pragma unroll
    for (int u = 0; u < 16; ++u) {
        const int d = t * 16 + u;
        const int kj = d & 31, n = (d >> 5) & 63, kk = d >> 11;
        Dp[d] = f2b(Sp[(size_t)(kk * 32 + kj) * 64 + n]);
    }
}

// ------- attn = Q @ S_bh via MFMA; block: 128 rows x 64 cols (one head) -------
// grid (8 heads, 128 row-tiles over merged M)
__global__ __launch_bounds__(256) void attn_mfma(
    const unsigned short* __restrict__ QKV, const unsigned short* __restrict__ Sbt,
    unsigned short* __restrict__ Ob)
{
    __shared__ __align__(16) unsigned short At[2 * 128 * 32];
    __shared__ __align__(16) unsigned short Bt[2 * 64 * 32];
    const int h = blockIdx.x;
    const int rbase = blockIdx.y * 128;
    const int b = (rbase >> 11) & 3;
    const int bh = b * 8 + h;
    const int tid = threadIdx.x;
    const int lane = tid & 63;
    const int w = tid >> 6;
    const int lr = lane & 15;
    const int quad = lane >> 4;

    {
        const int rloc = tid >> 2, c8 = (tid & 3) * 8;
#pragma unroll
        for (int it = 0; it < 4; ++it) {
            const int kk = it & 1, rh = it >> 1;
            const unsigned short* g = QKV +
                ((size_t)rbase + rh * 64 + rloc) * 1536 + h * 64 + kk * 32 + c8;
            GLD16(g, At + kk * 4096 + rh * 2048 + w * 512);
        }
        const unsigned short* Sg = Sbt + (size_t)bh * 4096 + tid * 8;
#pragma unroll
        for (int bi = 0; bi < 2; ++bi)
            GLD16(Sg + bi * 2048, Bt + bi * 2048 + w * 512);
    }
    __syncthreads();

    frag_cd acc[2][4] = {};
#pragma unroll
    for (int kk = 0; kk < 2; ++kk) {
        frag_ab a[2], bfr[4];
#pragma unroll
        for (int i = 0; i < 2; ++i)
            a[i] = *(const frag_ab*)&At[kk * 4096 + (w * 32 + i * 16 + lr) * 32 + quad * 8];
#pragma unroll
        for (int j = 0; j < 4; ++j)
            bfr[j] = *(const frag_ab*)&Bt[kk * 2048 + (j * 16 + lr) * 32 + quad * 8];
#pragma unroll
        for (int i = 0; i < 2; ++i)
#pragma unroll
            for (int j = 0; j < 4; ++j)
                acc[i][j] = __builtin_amdgcn_mfma_f32_16x16x32_bf16(a[i], bfr[j], acc[i][j], 0, 0, 0);
    }

#pragma unroll
    for (int i = 0; i < 2; ++i) {
        const int rowb = rbase + w * 32 + i * 16 + quad * 4;
#pragma unroll
        for (int j = 0; j < 4; ++j) {
            const int col = h * 64 + j * 16 + lr;
#pragma unroll
            for (int r = 0; r < 4; ++r)
                Ob[(size_t)(rowb + r) * 512 + col] = f2b(acc[i][j][r]);
        }
    }
}

// ------- LN1: x = LN(y0 + residual(inputs) + bo) -> xb bf16 -------
__global__ __launch_bounds__(256) void ln_make_bf16(
    const float* __restrict__ Y0, const float* __restrict__ question,
    const float* __restrict__ query, const float* __restrict__ bo,
    const float* __restrict__ g, const float* __restrict__ bta,
    unsigned short* __restrict__ Xb)
{
    __shared__ float red[256];
    const int row = blockIdx.x;
    const int t = threadIdx.x;
    const float* yr = Y0 + (size_t)row * Dq;
    const float* res = (row < 8192) ? question + (size_t)row * Dq
                                    : query + (size_t)(row - 8192) * Dq;
    float v0 = yr[t] + res[t] + bo[t];
    float v1 = yr[t + 256] + res[t + 256] + bo[t + 256];
    red[t] = v0 + v1;
    __syncthreads();
    for (int s = 128; s > 0; s >>= 1) { if (t < s) red[t] += red[t + s]; __syncthreads(); }
    const float mean = red[0] * (1.f / Dq);
    __syncthreads();
    const float d0 = v0 - mean, d1 = v1 - mean;
    red[t] = d0 * d0 + d1 * d1;
    __syncthreads();
    for (int s = 128; s > 0; s >>= 1) { if (t < s) red[t] += red[t + s]; __syncthreads(); }
    const float rstd = rsqrtf(red[0] * (1.f / Dq) + 1e-5f);
    unsigned short* xb = Xb + (size_t)row * Dq;
    xb[t] = f2b(d0 * rstd * g[t] + bta[t]);
    xb[t + 256] = f2b(d1 * rstd * g[t + 256] + bta[t + 256]);
}

// ------- LN2: out = LN(p0 + p1 + b2 + x(bf16)) -> out half-columns -------
// grid 8192 (rows of one chunk); xb offset per chunk passed in
__global__ __launch_bounds__(256) void ln_final(
    const float* __restrict__ P0, const float* __restrict__ P1,
    const unsigned short* __restrict__ Xbc, const float* __restrict__ b2,
    const float* __restrict__ g, const float* __restrict__ bta,
    float* __restrict__ out, int halfOff)
{
    __shared__ float red[256];
    const int row = blockIdx.x;
    const int t = threadIdx.x;
    const float* p0 = P0 + (size_t)row * Dq;
    const float* p1 = P1 + (size_t)row * Dq;
    const unsigned short* xr = Xbc + (size_t)row * Dq;
    float v0 = p0[t] + p1[t] + b2[t] + b2f(xr[t]);
    float v1 = p0[t + 256] + p1[t + 256] + b2[t + 256] + b2f(xr[t + 256]);
    red[t] = v0 + v1;
    __syncthreads();
    for (int s = 128; s > 0; s >>= 1) { if (t < s) red[t] += red[t + s]; __syncthreads(); }
    const float mean = red[0] * (1.f / Dq);
    __syncthreads();
    const float d0 = v0 - mean, d1 = v1 - mean;
    red[t] = d0 * d0 + d1 * d1;
    __syncthreads();
    for (int s = 128; s > 0; s >>= 1) { if (t < s) red[t] += red[t + s]; __syncthreads(); }
    const float rstd = rsqrtf(red[0] * (1.f / Dq) + 1e-5f);
    float* orow = out + (size_t)row * 1024 + halfOff;
    orow[t] = d0 * rstd * g[t] + bta[t];
    orow[t + 256] = d1 * rstd * g[t + 256] + bta[t + 256];
}

extern "C" void kernel_launch(void* const* d_in, const int* in_sizes, int n_in,
                              void* d_out, int out_size, void* d_ws, size_t ws_size,
                              hipStream_t stream)
{
    const float* question = (const float*)d_in[0];
    const float* query    = (const float*)d_in[1];
    const float* Wq = (const float*)d_in[2];  const float* bqp = (const float*)d_in[3];
    const float* Wk = (const float*)d_in[4];  const float* bkp = (const float*)d_in[5];
    const float* Wv = (const float*)d_in[6];  const float* bvp = (const float*)d_in[7];
    const float* Wo = (const float*)d_in[8];  const float* bo  = (const float*)d_in[9];
    const float* ln_g = (const float*)d_in[10]; const float* ln_b = (const float*)d_in[11];
    const float* W1 = (const float*)d_in[12]; const float* b1 = (const float*)d_in[13];
    const float* W2 = (const float*)d_in[14]; const float* b2 = (const float*)d_in[15];
    float* out = (float*)d_out;
    char* ws = (char*)d_ws;

    // ---- workspace layout (bytes), total ~87 MiB ----
    // phase A: QKVb [0,48M) bf16 [16384,1536]; attnb [48,64M) bf16 [16384,512];
    //          Xb [64,80M) bf16 [16384,512]
    // phase B: y0 f32 [0,32M) (dead after LN1); xb bf16 [32,48M) (alive to end);
    //          h bf16 [0,32M) per 8192-row chunk; p0 [48,64M), p1 [64,80M) f32
    // fixed:   S f32 [80M,+512K), weights bf16, Sbt, bqkv
    unsigned short* QKVb  = (unsigned short*)(ws);
    unsigned short* attnb = (unsigned short*)(ws + 48 * MiBu);
    unsigned short* Xb    = (unsigned short*)(ws + 64 * MiBu);
    float*          y0    = (float*)(ws);
    unsigned short* xb    = (unsigned short*)(ws + 32 * MiBu);
    unsigned short* hb    = (unsigned short*)(ws);
    float*          p0    = (float*)(ws + 48 * MiBu);
    float*          p1    = (float*)(ws + 64 * MiBu);
    float* S = (float*)(ws + 80 * MiBu);
    char* wp = ws + 80 * MiBu + 524288;
    unsigned short* Wqkvb = (unsigned short*)wp;  wp += 1536 * 512 * 2;
    unsigned short* Wob   = (unsigned short*)wp;  wp += 512 * 512 * 2;
    unsigned short* W1b   = (unsigned short*)wp;  wp += 2048 * 512 * 2;
    unsigned short* W2b   = (unsigned short*)wp;  wp += 512 * 2048 * 2;
    unsigned short* Sbt   = (unsigned short*)wp;  wp += 32 * 4096 * 2;
    float* bqkv           = (float*)wp;

    dim3 blk(256);

    // conversions + S zero + bias concat (one dispatch)
    convert_all<<<11398, blk, 0, stream>>>(Wq, Wk, Wv, Wo, W1, W2, question, query,
                                           bqp, bkp, bvp,
                                           Wqkvb, Wob, W1b, W2b, Xb, S, bqkv);

    // QKV GEMM merged: [16384,512] @ [1536,512]^T -> bf16 (1536 blocks, 6/CU)
    gemm_bf16<<<dim3(12, 128), blk, 0, stream>>>(Xb, Wqkvb, bqkv, nullptr, QKVb,
                                                 Mrows, 1536, 512, 0);

    // S (fp32 accum over both halves) -> bf16 B-layout; attn via MFMA (1024 blocks)
    s_kernel<<<dim3(32, 16), blk, 0, stream>>>(QKVb, S);
    sbt_convert<<<32, blk, 0, stream>>>(S, Sbt);
    attn_mfma<<<dim3(8, 128), blk, 0, stream>>>(QKVb, Sbt, attnb);

    // o-proj merged, no split-K (512 blocks, 2/CU): y0 = attn @ Wo^T (f32)
    gemm_bf16<<<dim3(4, 128), blk, 0, stream>>>(attnb, Wob, nullptr, y0, nullptr,
                                                Mrows, 512, 512, 0);

    // LN1: xb = LN(y0 + input + bo) in bf16 (residual from pristine inputs)
    ln_make_bf16<<<Mrows, blk, 0, stream>>>(y0, question, query, bo, ln_g, ln_b, xb);

    // FFN in 2 chunks of 8192 rows (h reuses y0 region)
    for (int c = 0; c < 2; ++c) {
        const unsigned short* xbc = xb + (size_t)c * 8192 * Dq;
        // FFN1: h = relu(x @ W1^T + b1) -> bf16 [8192,2048] (1024 blocks)
        gemm_bf16<<<dim3(16, 64), blk, 0, stream>>>(xbc, W1b, b1, nullptr, hb,
                                                    8192, PFq, 512, 1);
        // FFN2 split-K=2 partials, plain stores (512 blocks, 2/CU)
        gemm_bf16_partk<<<dim3(4, 64, 2), blk, 0, stream>>>(hb, W2b, p0,
                                                            (size_t)(16 * MiBu / 4),
                                                            8192, 512, PFq, 1024);
        // LN2: out(:, c*512 : c*512+512) = LN(p0+p1+b2+x)
        ln_final<<<8192, blk, 0, stream>>>(p0, p1, xbc, b2, ln_g, ln_b, out, c * 512);
    }
}